// Round 9
// baseline (575.822 us; speedup 1.0000x reference)
//
#include <hip/hip_runtime.h>

// HeteroGraphSAGE on MI355X — fp32 I/O, bf16 MFMA internals.
// R9: (1) NO __syncthreads in sage kernels — LDS tiles are per-wave private
//     (in-order DS pipe guarantees RAW within a wave); waves fully independent.
//     (2) gather MLP 2x: KF=64 -> 8 nbr-groups x 8 feat-lanes (16 nbrs/step);
//     KF=128 -> 2-row interleave (4 independent b128 loads in flight).
//     (3) heads fused into sage_pair128 epilogue via per-wave LDS round trip
//     (C-layout -> A-layout), deleting head_pair + its 76MB re-read.
// Dispatches: memset, prep, sage_pair64, sage_pair128(+heads).
//
// ws layout (bytes):
//   cnt_m @0  cnt_c @256K  bucket_m @1MiB (u32)  bucket_c @14MiB (u16)
//   h_m @27MiB (bf16)  packed @40MiB (10*32KiB)
//   shadow (ws>=87MiB): xc_bf @41MiB  xm_bf @54MiB  hc_bf @61MiB

typedef unsigned short u16;
typedef unsigned int u32;
typedef short bf16x8 __attribute__((ext_vector_type(8)));
typedef float f32x4 __attribute__((ext_vector_type(4)));
typedef u16 u16x4 __attribute__((ext_vector_type(4)));
typedef u16 u16x8 __attribute__((ext_vector_type(8)));

#define CAP 64
#define LDS_PAD 8
#define NXCD 8
#define ECHUNK 64
#define NBUILD (NXCD * ECHUNK * 2)   // 1024
#define NPACK  768                   // 64 x 12

__device__ __forceinline__ float bf2f(u16 u) {
    union { u32 i; float f; } v; v.i = ((u32)u) << 16; return v.f;
}
__device__ __forceinline__ u16 f2bf(float f) {
    union { float f; u32 i; } v; v.f = f;
    u32 i = v.i;
    return (u16)((i + 0x7FFFu + ((i >> 16) & 1u)) >> 16);   // RNE
}
__device__ __forceinline__ bf16x8 cvt8(const float* p) {
    bf16x8 r;
#pragma unroll
    for (int i = 0; i < 8; ++i) r[i] = (short)f2bf(p[i]);
    return r;
}

// ---------------- prep: build + pack + converts in one dispatch ----------------
struct PackDesc { const float* src; u16* dst; int K; int Nsrc; int ntOff; };
struct PrepArgs {
    const int* src_cm; const int* dst_cm; const int* src_mc; const int* dst_mc;
    int* cnt_m; u32* bucket_m; int* cnt_c; u16* bucket_c;
    int E; int nMerch; int nCard;
    const float* xc; u16* xcb; int ncBlk;
    const float* xm; u16* xmb; int nmBlk;
    PackDesc pd[12];
};

__global__ void __launch_bounds__(256) prep(PrepArgs a) {
    const int b = blockIdx.x;
    if (b < NBUILD) {
        const int g = b & 7;
        const int chunk = (b >> 3) & 63;
        const bool dirA = b < (NBUILD / 2);
        const int nNode = dirA ? a.nMerch : a.nCard;
        const int lo = (int)((long long)g * nNode / NXCD);
        const int hi = (int)((long long)(g + 1) * nNode / NXCD);
        const int* dst = dirA ? a.dst_cm : a.dst_mc;
        const int* src = dirA ? a.src_cm : a.src_mc;
        int* cnt = dirA ? a.cnt_m : a.cnt_c;
        const int e0 = (int)((long long)chunk * a.E / ECHUNK);
        const int e1 = (int)((long long)(chunk + 1) * a.E / ECHUNK);
        for (int i = e0 + threadIdx.x; i < e1; i += 256) {
            int d = __builtin_nontemporal_load(dst + i);
            if (d >= lo && d < hi) {
                int slot = atomicAdd(&cnt[d], 1);
                if (slot < CAP) {
                    int s = __builtin_nontemporal_load(src + i);
                    if (dirA) a.bucket_m[(size_t)d * CAP + slot] = (u32)s;
                    else      a.bucket_c[(size_t)d * CAP + slot] = (u16)s;
                }
            }
        }
    } else if (b < NBUILD + NPACK) {
        int e = b - NBUILD;
        PackDesc pd = a.pd[e >> 6];
        int idx = (e & 63) * 256 + threadIdx.x;
        int j = idx & 7;
        int lane = (idx >> 3) & 63;
        int t = idx >> 9;
        int nLocal = pd.Nsrc >> 4;
        int ntl = t % nLocal;
        int kt = t / nLocal;
        if (kt >= (pd.K >> 5)) return;
        int k = kt * 32 + ((lane >> 4) << 3) + j;
        int n = ntl * 16 + (lane & 15);
        pd.dst[(((kt * 8 + pd.ntOff + ntl) * 64) + lane) * 8 + j] = f2bf(pd.src[k * pd.Nsrc + n]);
    } else {
        int e = b - NBUILD - NPACK;
        const float* s;
        u16* d;
        int n;
        if (e < a.ncBlk) { s = a.xc; d = a.xcb; n = a.nCard * 64; }
        else             { e -= a.ncBlk; s = a.xm; d = a.xmb; n = a.nMerch * 64; }
        int i = (e * 256 + threadIdx.x) * 4;
        if (i >= n) return;
        f32x4 v = *reinterpret_cast<const f32x4*>(s + i);
        u16x4 o;
#pragma unroll
        for (int j = 0; j < 4; ++j) o[j] = f2bf(v[j]);
        *reinterpret_cast<u16x4*>(d + i) = o;
    }
}

// ---------------- SAGE job descriptor ----------------
struct SageJob {
    const u16* src;      // bf16 gather source [*, KF]
    const void* adj;     // bucket rows, CAP wide (u32 if idx32 else u16)
    const int* cnt;
    const u16* Wlp;      // packed Wl fragments
    const u16* dst;      // bf16 lin_r source [M, KF]
    const u16* Wrp;
    const float* bias;   // [128]
    float* outF;         // fp32 out [M,128] or null
    u16* outH;           // bf16 out or null
    u16* outS;           // bf16 shadow out or null
    int M;
    int idx32;
    int nBlk;
    // fused head (sage_pair128 only; active when pred != null)
    const u16* hW1p;     // packed [cW1 | rW1]
    const float* hb1a;   // cb1
    const float* hb1b;   // rb1
    const float* cW2; const float* cb2;
    const float* rW2; const float* rb2;
    float* pred; float* risk;
};

// ---------------- sage_pair64: L0 both directions, KF=64 ----------------
// Gather: 8 nbr-groups x 8 feat-lanes x 2 banks = 16 nbrs/step.
__global__ void __launch_bounds__(256) sage_pair64(SageJob j0, SageJob j1) {
    __shared__ alignas(16) u16 lds[4][16][64 + LDS_PAD];
    const bool second = (int)blockIdx.x >= j0.nBlk;
    const SageJob& j = second ? j1 : j0;
    const int bx = second ? blockIdx.x - j0.nBlk : blockIdx.x;
    const int lane = threadIdx.x & 63;
    const int wv = threadIdx.x >> 6;
    const int m0 = (bx * 4 + wv) * 16;
    if (m0 >= j.M) return;                 // M % 16 == 0 -> full tiles only
    const int quad = lane >> 4;
    const int l15 = lane & 15;
    const int nb8 = lane >> 3;
    const int fl8 = lane & 7;

    const u16* srcH = j.src;
    const u32* adj32 = (const u32*)j.adj;
    const u16* adj16 = (const u16*)j.adj;
    const bool i32 = (j.idx32 != 0);

    int cv = j.cnt[m0 + l15];
    int cc_n = min(__shfl(cv, 0), CAP);
    int sidx_n = 0;
    if (lane < cc_n)
        sidx_n = i32 ? (int)adj32[(size_t)m0 * CAP + lane]
                     : (int)adj16[(size_t)m0 * CAP + lane];
    for (int r = 0; r < 16; ++r) {
        const int cc = cc_n;
        const int cfull = __shfl(cv, r);
        const int sidx = sidx_n;
        if (r < 15) {
            cc_n = min(__shfl(cv, r + 1), CAP);
            sidx_n = 0;
            if (lane < cc_n)
                sidx_n = i32 ? (int)adj32[(size_t)(m0 + r + 1) * CAP + lane]
                             : (int)adj16[(size_t)(m0 + r + 1) * CAP + lane];
        }
        float a0[8], a1[8];
#pragma unroll
        for (int i = 0; i < 8; ++i) { a0[i] = 0.f; a1[i] = 0.f; }
        for (int t = 0; t < cc; t += 16) {
            int k0 = t + nb8;
            int k1 = t + nb8 + 8;
            int s0 = __shfl(sidx, k0);
            int s1 = __shfl(sidx, k1);
            bool p0 = k0 < cc;
            bool p1 = k1 < cc;
            bf16x8 u0 = *(const bf16x8*)(srcH + (size_t)s0 * 64 + fl8 * 8);
            bf16x8 u1 = *(const bf16x8*)(srcH + (size_t)s1 * 64 + fl8 * 8);
#pragma unroll
            for (int i = 0; i < 8; ++i) {
                a0[i] += p0 ? bf2f((u16)u0[i]) : 0.f;
                a1[i] += p1 ? bf2f((u16)u1[i]) : 0.f;
            }
        }
        float inv = 1.f / (float)max(cfull, 1);
        u16 packed[8];
#pragma unroll
        for (int i = 0; i < 8; ++i) {
            float m = a0[i] + a1[i];
            m += __shfl_xor(m, 8);
            m += __shfl_xor(m, 16);
            m += __shfl_xor(m, 32);
            packed[i] = f2bf(m * inv);
        }
        if (nb8 == 0) *(u16x8*)&lds[wv][r][fl8 * 8] = *(const u16x8*)packed;
    }
    // no barrier: tile is wave-private; DS pipe is in-order within a wave

    f32x4 acc[8];
#pragma unroll
    for (int i = 0; i < 8; ++i) acc[i] = (f32x4){0.f, 0.f, 0.f, 0.f};
#pragma unroll
    for (int kt = 0; kt < 2; ++kt) {
        bf16x8 a = *reinterpret_cast<const bf16x8*>(&lds[wv][l15][kt * 32 + quad * 8]);
#pragma unroll
        for (int nt = 0; nt < 8; ++nt) {
            bf16x8 b = *reinterpret_cast<const bf16x8*>(j.Wlp + (size_t)(((kt * 8 + nt) * 64 + lane) * 8));
            acc[nt] = __builtin_amdgcn_mfma_f32_16x16x32_bf16(a, b, acc[nt], 0, 0, 0);
        }
    }
#pragma unroll
    for (int kt = 0; kt < 2; ++kt) {
        bf16x8 a = *reinterpret_cast<const bf16x8*>(j.dst + (size_t)(m0 + l15) * 64 + kt * 32 + quad * 8);
#pragma unroll
        for (int nt = 0; nt < 8; ++nt) {
            bf16x8 b = *reinterpret_cast<const bf16x8*>(j.Wrp + (size_t)(((kt * 8 + nt) * 64 + lane) * 8));
            acc[nt] = __builtin_amdgcn_mfma_f32_16x16x32_bf16(a, b, acc[nt], 0, 0, 0);
        }
    }
#pragma unroll
    for (int nt = 0; nt < 8; ++nt) {
        int col = nt * 16 + l15;
        float bv = j.bias[col];
#pragma unroll
        for (int r = 0; r < 4; ++r) {
            int row = m0 + quad * 4 + r;
            float v = fmaxf(acc[nt][r] + bv, 0.f);
            if (j.outF) j.outF[(size_t)row * 128 + col] = v;
            if (j.outH) j.outH[(size_t)row * 128 + col] = f2bf(v);
            if (j.outS) j.outS[(size_t)row * 128 + col] = f2bf(v);
        }
    }
}

// ---------------- sage_pair128: L1 both directions + fused heads ----------------
// Gather: 2-row interleave, 4 independent b128 loads in flight.
__global__ void __launch_bounds__(256) sage_pair128(SageJob j0, SageJob j1) {
    __shared__ alignas(16) u16 lds[4][16][128 + LDS_PAD];
    const bool second = (int)blockIdx.x >= j0.nBlk;
    const SageJob& j = second ? j1 : j0;
    const int bx = second ? blockIdx.x - j0.nBlk : blockIdx.x;
    const int lane = threadIdx.x & 63;
    const int wv = threadIdx.x >> 6;
    const int m0 = (bx * 4 + wv) * 16;
    if (m0 >= j.M) return;
    const int quad = lane >> 4;
    const int l15 = lane & 15;

    const u16* srcH = j.src;
    const u32* adj32 = (const u32*)j.adj;
    const u16* adj16 = (const u16*)j.adj;
    const bool i32 = (j.idx32 != 0);

    int cv = j.cnt[m0 + l15];
    int ccA_n = min(__shfl(cv, 0), CAP);
    int ccB_n = min(__shfl(cv, 1), CAP);
    int sA_n = 0, sB_n = 0;
    if (lane < ccA_n)
        sA_n = i32 ? (int)adj32[(size_t)m0 * CAP + lane] : (int)adj16[(size_t)m0 * CAP + lane];
    if (lane < ccB_n)
        sB_n = i32 ? (int)adj32[(size_t)(m0 + 1) * CAP + lane] : (int)adj16[(size_t)(m0 + 1) * CAP + lane];

    for (int r = 0; r < 16; r += 2) {
        const int ccA = ccA_n, ccB = ccB_n;
        const int sidxA = sA_n, sidxB = sB_n;
        const int cfA = __shfl(cv, r);
        const int cfB = __shfl(cv, r + 1);
        if (r < 14) {
            ccA_n = min(__shfl(cv, r + 2), CAP);
            ccB_n = min(__shfl(cv, r + 3), CAP);
            sA_n = 0; sB_n = 0;
            if (lane < ccA_n)
                sA_n = i32 ? (int)adj32[(size_t)(m0 + r + 2) * CAP + lane] : (int)adj16[(size_t)(m0 + r + 2) * CAP + lane];
            if (lane < ccB_n)
                sB_n = i32 ? (int)adj32[(size_t)(m0 + r + 3) * CAP + lane] : (int)adj16[(size_t)(m0 + r + 3) * CAP + lane];
        }
        float aA0[8], aA1[8], aB0[8], aB1[8];
#pragma unroll
        for (int i = 0; i < 8; ++i) { aA0[i] = 0.f; aA1[i] = 0.f; aB0[i] = 0.f; aB1[i] = 0.f; }
        int cmax = max(ccA, ccB);
        for (int t = 0; t < cmax; t += 8) {
            int k0 = t + quad;
            int k1 = t + quad + 4;
            int sA0 = __shfl(sidxA, k0), sA1 = __shfl(sidxA, k1);
            int sB0 = __shfl(sidxB, k0), sB1 = __shfl(sidxB, k1);
            bool pA0 = k0 < ccA, pA1 = k1 < ccA;
            bool pB0 = k0 < ccB, pB1 = k1 < ccB;
            bf16x8 uA0 = *(const bf16x8*)(srcH + (size_t)sA0 * 128 + l15 * 8);
            bf16x8 uA1 = *(const bf16x8*)(srcH + (size_t)sA1 * 128 + l15 * 8);
            bf16x8 uB0 = *(const bf16x8*)(srcH + (size_t)sB0 * 128 + l15 * 8);
            bf16x8 uB1 = *(const bf16x8*)(srcH + (size_t)sB1 * 128 + l15 * 8);
#pragma unroll
            for (int i = 0; i < 8; ++i) {
                aA0[i] += pA0 ? bf2f((u16)uA0[i]) : 0.f;
                aA1[i] += pA1 ? bf2f((u16)uA1[i]) : 0.f;
                aB0[i] += pB0 ? bf2f((u16)uB0[i]) : 0.f;
                aB1[i] += pB1 ? bf2f((u16)uB1[i]) : 0.f;
            }
        }
        float invA = 1.f / (float)max(cfA, 1);
        float invB = 1.f / (float)max(cfB, 1);
        u16 pkA[8], pkB[8];
#pragma unroll
        for (int i = 0; i < 8; ++i) {
            float mA = aA0[i] + aA1[i];
            mA += __shfl_xor(mA, 16);
            mA += __shfl_xor(mA, 32);
            pkA[i] = f2bf(mA * invA);
            float mB = aB0[i] + aB1[i];
            mB += __shfl_xor(mB, 16);
            mB += __shfl_xor(mB, 32);
            pkB[i] = f2bf(mB * invB);
        }
        if (quad == 0) {
            *(u16x8*)&lds[wv][r][l15 * 8] = *(const u16x8*)pkA;
            *(u16x8*)&lds[wv][r + 1][l15 * 8] = *(const u16x8*)pkB;
        }
    }
    // no barrier: wave-private tile

    f32x4 acc[8];
#pragma unroll
    for (int i = 0; i < 8; ++i) acc[i] = (f32x4){0.f, 0.f, 0.f, 0.f};
#pragma unroll
    for (int kt = 0; kt < 4; ++kt) {
        bf16x8 a = *reinterpret_cast<const bf16x8*>(&lds[wv][l15][kt * 32 + quad * 8]);
#pragma unroll
        for (int nt = 0; nt < 8; ++nt) {
            bf16x8 b = *reinterpret_cast<const bf16x8*>(j.Wlp + (size_t)(((kt * 8 + nt) * 64 + lane) * 8));
            acc[nt] = __builtin_amdgcn_mfma_f32_16x16x32_bf16(a, b, acc[nt], 0, 0, 0);
        }
    }
#pragma unroll
    for (int kt = 0; kt < 4; ++kt) {
        bf16x8 a = *reinterpret_cast<const bf16x8*>(j.dst + (size_t)(m0 + l15) * 128 + kt * 32 + quad * 8);
#pragma unroll
        for (int nt = 0; nt < 8; ++nt) {
            bf16x8 b = *reinterpret_cast<const bf16x8*>(j.Wrp + (size_t)(((kt * 8 + nt) * 64 + lane) * 8));
            acc[nt] = __builtin_amdgcn_mfma_f32_16x16x32_bf16(a, b, acc[nt], 0, 0, 0);
        }
    }
    // epilogue: write h (fp32) to global + bf16 tile to LDS (A-layout source for head)
#pragma unroll
    for (int nt = 0; nt < 8; ++nt) {
        int col = nt * 16 + l15;
        float bv = j.bias[col];
#pragma unroll
        for (int r = 0; r < 4; ++r) {
            int row = m0 + quad * 4 + r;
            float v = fmaxf(acc[nt][r] + bv, 0.f);
            if (j.outF) j.outF[(size_t)row * 128 + col] = v;
            lds[wv][quad * 4 + r][col] = f2bf(v);
        }
    }

    if (!j.pred) return;
    // ---- fused head: hidden = relu(h @ [cW1|rW1] + [cb1|rb1]) ----
    f32x4 hacc[8];
#pragma unroll
    for (int i = 0; i < 8; ++i) hacc[i] = (f32x4){0.f, 0.f, 0.f, 0.f};
#pragma unroll
    for (int kt = 0; kt < 4; ++kt) {
        bf16x8 a = *reinterpret_cast<const bf16x8*>(&lds[wv][l15][kt * 32 + quad * 8]);
#pragma unroll
        for (int nt = 0; nt < 8; ++nt) {
            bf16x8 b = *reinterpret_cast<const bf16x8*>(j.hW1p + (size_t)(((kt * 8 + nt) * 64 + lane) * 8));
            hacc[nt] = __builtin_amdgcn_mfma_f32_16x16x32_bf16(a, b, hacc[nt], 0, 0, 0);
        }
    }
#pragma unroll
    for (int nt = 0; nt < 8; ++nt) {
        int col = nt * 16 + l15;
        float bv = (col < 64) ? j.hb1a[col] : j.hb1b[col - 64];
#pragma unroll
        for (int r = 0; r < 4; ++r) {
            float v = fmaxf(hacc[nt][r] + bv, 0.f);
            lds[wv][quad * 4 + r][col] = f2bf(v);
        }
    }
    // ---- head-2: pred = t1 @ cW2 + cb2 ; risk = sigmoid(t2 @ rW2 + rb2) ----
    float w0 = j.cW2[lane * 2 + 0];
    float w1 = j.cW2[lane * 2 + 1];
    float w2 = j.rW2[lane];
    float cb0 = j.cb2[0], cb1v = j.cb2[1], rb = j.rb2[0];
    for (int r = 0; r < 16; ++r) {
        float t1 = bf2f(lds[wv][r][lane]);
        float t2 = bf2f(lds[wv][r][64 + lane]);
        float s0 = t1 * w0;
        float s1 = t1 * w1;
        float s2 = t2 * w2;
        for (int off = 32; off > 0; off >>= 1) {
            s0 += __shfl_xor(s0, off);
            s1 += __shfl_xor(s1, off);
            s2 += __shfl_xor(s2, off);
        }
        if (lane == 0) {
            int row = m0 + r;
            j.pred[(size_t)row * 2 + 0] = s0 + cb0;
            j.pred[(size_t)row * 2 + 1] = s1 + cb1v;
            float z = s2 + rb;
            j.risk[row] = 1.f / (1.f + __expf(-z));
        }
    }
}

// ---------------- fallback SAGE (fp32 sources, no shadow ws) ----------------
template<typename IdxT, int KF, bool SRCF, bool DSTF, bool OUTF>
__global__ void __launch_bounds__(256) sage_fused(
    const void* __restrict__ Xsrc_, const IdxT* __restrict__ adj,
    const int* __restrict__ cnt,
    const u16* __restrict__ Wlp, const void* __restrict__ Xdst_,
    const u16* __restrict__ Wrp, const float* __restrict__ bias,
    void* __restrict__ out_, int M)
{
    constexpr int NV = KF / 16;
    __shared__ alignas(16) u16 lds[4][16][128 + LDS_PAD];
    const int lane = threadIdx.x & 63;
    const int wv = threadIdx.x >> 6;
    const int m0 = (blockIdx.x * 4 + wv) * 16;
    if (m0 >= M) return;
    const int quad = lane >> 4;
    const int l15 = lane & 15;

    {
        const float* srcF = (const float*)Xsrc_;
        const u16*   srcH = (const u16*)Xsrc_;
        for (int r = 0; r < 16; ++r) {
            int node = m0 + r;
            int c = cnt[node];
            int cc = min(c, CAP);
            int sidx = (lane < cc) ? (int)adj[(size_t)node * CAP + lane] : 0;
            float inv = 1.f / (float)max(c, 1);
            float acc0[NV], acc1[NV];
#pragma unroll
            for (int i = 0; i < NV; ++i) { acc0[i] = 0.f; acc1[i] = 0.f; }
            for (int t = 0; t < cc; t += 8) {
                int k0 = t + quad, k1 = t + quad + 4;
                int s0 = __shfl(sidx, k0), s1 = __shfl(sidx, k1);
                bool p0 = k0 < cc, p1 = k1 < cc;
                if constexpr (SRCF) {
                    const f32x4* q0 = (const f32x4*)(srcF + (size_t)s0 * KF + l15 * NV);
                    const f32x4* q1 = (const f32x4*)(srcF + (size_t)s1 * KF + l15 * NV);
                    f32x4 u0 = q0[0], u1 = q1[0];
                    if constexpr (NV == 8) {
                        f32x4 w0 = q0[1], w1 = q1[1];
#pragma unroll
                        for (int i = 0; i < 4; ++i) {
                            acc0[4 + i] += p0 ? w0[i] : 0.f;
                            acc1[4 + i] += p1 ? w1[i] : 0.f;
                        }
                    }
#pragma unroll
                    for (int i = 0; i < 4; ++i) {
                        acc0[i] += p0 ? u0[i] : 0.f;
                        acc1[i] += p1 ? u1[i] : 0.f;
                    }
                } else {
                    if constexpr (NV == 8) {
                        bf16x8 u0 = *(const bf16x8*)(srcH + (size_t)s0 * KF + l15 * 8);
                        bf16x8 u1 = *(const bf16x8*)(srcH + (size_t)s1 * KF + l15 * 8);
#pragma unroll
                        for (int i = 0; i < 8; ++i) {
                            acc0[i] += p0 ? bf2f((u16)u0[i]) : 0.f;
                            acc1[i] += p1 ? bf2f((u16)u1[i]) : 0.f;
                        }
                    } else {
                        u16x4 u0 = *(const u16x4*)(srcH + (size_t)s0 * KF + l15 * 4);
                        u16x4 u1 = *(const u16x4*)(srcH + (size_t)s1 * KF + l15 * 4);
#pragma unroll
                        for (int i = 0; i < 4; ++i) {
                            acc0[i] += p0 ? bf2f(u0[i]) : 0.f;
                            acc1[i] += p1 ? bf2f(u1[i]) : 0.f;
                        }
                    }
                }
            }
            u16 packed[NV];
#pragma unroll
            for (int i = 0; i < NV; ++i) {
                float m = acc0[i] + acc1[i];
                m += __shfl_xor(m, 16);
                m += __shfl_xor(m, 32);
                packed[i] = f2bf(m * inv);
            }
            if (quad == 0) {
                if constexpr (NV == 8) *(u16x8*)&lds[wv][r][l15 * 8] = *(const u16x8*)packed;
                else                   *(u16x4*)&lds[wv][r][l15 * 4] = *(const u16x4*)packed;
            }
        }
    }

    constexpr int KT = KF >> 5;
    f32x4 acc[8];
#pragma unroll
    for (int i = 0; i < 8; ++i) acc[i] = (f32x4){0.f, 0.f, 0.f, 0.f};
#pragma unroll
    for (int kt = 0; kt < KT; ++kt) {
        bf16x8 a = *reinterpret_cast<const bf16x8*>(&lds[wv][l15][kt * 32 + quad * 8]);
#pragma unroll
        for (int nt = 0; nt < 8; ++nt) {
            bf16x8 b = *reinterpret_cast<const bf16x8*>(Wlp + (size_t)(((kt * 8 + nt) * 64 + lane) * 8));
            acc[nt] = __builtin_amdgcn_mfma_f32_16x16x32_bf16(a, b, acc[nt], 0, 0, 0);
        }
    }
#pragma unroll
    for (int kt = 0; kt < KT; ++kt) {
        bf16x8 a;
        if constexpr (DSTF) a = cvt8((const float*)Xdst_ + (size_t)(m0 + l15) * KF + kt * 32 + quad * 8);
        else                a = *reinterpret_cast<const bf16x8*>((const u16*)Xdst_ + (size_t)(m0 + l15) * KF + kt * 32 + quad * 8);
#pragma unroll
        for (int nt = 0; nt < 8; ++nt) {
            bf16x8 b = *reinterpret_cast<const bf16x8*>(Wrp + (size_t)(((kt * 8 + nt) * 64 + lane) * 8));
            acc[nt] = __builtin_amdgcn_mfma_f32_16x16x32_bf16(a, b, acc[nt], 0, 0, 0);
        }
    }
#pragma unroll
    for (int nt = 0; nt < 8; ++nt) {
        int col = nt * 16 + l15;
        float bv = bias[col];
#pragma unroll
        for (int r = 0; r < 4; ++r) {
            int row = m0 + quad * 4 + r;
            float v = fmaxf(acc[nt][r] + bv, 0.f);
            if constexpr (OUTF) ((float*)out_)[(size_t)row * 128 + col] = v;
            else                ((u16*)out_)[(size_t)row * 128 + col] = f2bf(v);
        }
    }
}

// ---------------- fallback heads ----------------
struct HeadJob {
    const float* X; const u16* W1p;
    const float* b1a; const float* b1b;
    const float* cW2; const float* cb2;
    const float* rW2; const float* rb2;
    float* pred; float* risk; int M; int nBlk;
};

__global__ void __launch_bounds__(256) head_pair(HeadJob h0, HeadJob h1) {
    __shared__ alignas(16) u16 lds[4][16][128 + LDS_PAD];
    const bool second = (int)blockIdx.x >= h0.nBlk;
    const HeadJob& h = second ? h1 : h0;
    const int bx = second ? blockIdx.x - h0.nBlk : blockIdx.x;
    const int lane = threadIdx.x & 63;
    const int wv = threadIdx.x >> 6;
    const int m0 = (bx * 4 + wv) * 16;
    if (m0 >= h.M) return;
    const int quad = lane >> 4;
    const int l15 = lane & 15;

    f32x4 acc[8];
#pragma unroll
    for (int i = 0; i < 8; ++i) acc[i] = (f32x4){0.f, 0.f, 0.f, 0.f};
#pragma unroll
    for (int kt = 0; kt < 4; ++kt) {
        bf16x8 a = cvt8(h.X + (size_t)(m0 + l15) * 128 + kt * 32 + quad * 8);
#pragma unroll
        for (int nt = 0; nt < 8; ++nt) {
            bf16x8 b = *reinterpret_cast<const bf16x8*>(h.W1p + (size_t)(((kt * 8 + nt) * 64 + lane) * 8));
            acc[nt] = __builtin_amdgcn_mfma_f32_16x16x32_bf16(a, b, acc[nt], 0, 0, 0);
        }
    }
#pragma unroll
    for (int nt = 0; nt < 8; ++nt) {
        int col = nt * 16 + l15;
        float bv = (col < 64) ? h.b1a[col] : h.b1b[col - 64];
#pragma unroll
        for (int r = 0; r < 4; ++r) {
            float v = fmaxf(acc[nt][r] + bv, 0.f);
            lds[wv][quad * 4 + r][col] = f2bf(v);
        }
    }

    float w0 = h.cW2[lane * 2 + 0];
    float w1 = h.cW2[lane * 2 + 1];
    float w2 = h.rW2[lane];
    float cb0 = h.cb2[0], cb1v = h.cb2[1], rb = h.rb2[0];
    for (int r = 0; r < 16; ++r) {
        float t1 = bf2f(lds[wv][r][lane]);
        float t2 = bf2f(lds[wv][r][64 + lane]);
        float s0 = t1 * w0;
        float s1 = t1 * w1;
        float s2 = t2 * w2;
        for (int off = 32; off > 0; off >>= 1) {
            s0 += __shfl_xor(s0, off);
            s1 += __shfl_xor(s1, off);
            s2 += __shfl_xor(s2, off);
        }
        if (lane == 0) {
            int row = m0 + r;
            h.pred[(size_t)row * 2 + 0] = s0 + cb0;
            h.pred[(size_t)row * 2 + 1] = s1 + cb1v;
            float z = s2 + rb;
            h.risk[row] = 1.f / (1.f + __expf(-z));
        }
    }
}

// ---------------- host ----------------
#define OFF_CNT_M  ((size_t)0)
#define OFF_CNT_C  ((size_t)262144)
#define OFF_BKT_M  ((size_t)1  << 20)
#define OFF_BKT_C  ((size_t)14 << 20)
#define OFF_HM     ((size_t)27 << 20)
#define OFF_PACK   ((size_t)40 << 20)
#define OFF_XC     ((size_t)41 << 20)
#define OFF_XM     ((size_t)54 << 20)
#define OFF_HCB    ((size_t)61 << 20)
#define WS_SHADOW_NEED ((size_t)87 << 20)

extern "C" void kernel_launch(void* const* d_in, const int* in_sizes, int n_in,
                              void* d_out, int out_size, void* d_ws, size_t ws_size,
                              hipStream_t stream)
{
    const float* x_card   = (const float*)d_in[0];
    const float* x_merch  = (const float*)d_in[1];
    const int* src_cm     = (const int*)d_in[2];
    const int* dst_cm     = (const int*)d_in[3];
    const int* src_mc     = (const int*)d_in[4];
    const int* dst_mc     = (const int*)d_in[5];
    const float* Wl0_cm   = (const float*)d_in[6];
    const float* bl0_cm   = (const float*)d_in[7];
    const float* Wr0_cm   = (const float*)d_in[8];
    const float* Wl0_mc   = (const float*)d_in[9];
    const float* bl0_mc   = (const float*)d_in[10];
    const float* Wr0_mc   = (const float*)d_in[11];
    const float* Wl1_cm   = (const float*)d_in[12];
    const float* bl1_cm   = (const float*)d_in[13];
    const float* Wr1_cm   = (const float*)d_in[14];
    const float* Wl1_mc   = (const float*)d_in[15];
    const float* bl1_mc   = (const float*)d_in[16];
    const float* Wr1_mc   = (const float*)d_in[17];
    const float* cW1_card = (const float*)d_in[18];
    const float* cb1_card = (const float*)d_in[19];
    const float* cW2_card = (const float*)d_in[20];
    const float* cb2_card = (const float*)d_in[21];
    const float* cW1_mer  = (const float*)d_in[22];
    const float* cb1_mer  = (const float*)d_in[23];
    const float* cW2_mer  = (const float*)d_in[24];
    const float* cb2_mer  = (const float*)d_in[25];
    const float* rW1      = (const float*)d_in[26];
    const float* rb1      = (const float*)d_in[27];
    const float* rW2      = (const float*)d_in[28];
    const float* rb2      = (const float*)d_in[29];

    const int nCard  = in_sizes[0] / 64;   // 100000
    const int nMerch = in_sizes[1] / 64;   // 50000
    const int E      = in_sizes[2];        // 1000000

    char* ws = (char*)d_ws;
    int* cnt_m    = (int*)(ws + OFF_CNT_M);
    int* cnt_c    = (int*)(ws + OFF_CNT_C);
    u32* bucket_m = (u32*)(ws + OFF_BKT_M);
    u16* bucket_c = (u16*)(ws + OFF_BKT_C);
    u16* h_m      = (u16*)(ws + OFF_HM);
    u16* pw       = (u16*)(ws + OFF_PACK);
    u16* pWl0_cm = pw + 0 * 16384;
    u16* pWr0_cm = pw + 1 * 16384;
    u16* pWl0_mc = pw + 2 * 16384;
    u16* pWr0_mc = pw + 3 * 16384;
    u16* pWl1_cm = pw + 4 * 16384;
    u16* pWr1_cm = pw + 5 * 16384;
    u16* pWl1_mc = pw + 6 * 16384;
    u16* pWr1_mc = pw + 7 * 16384;
    u16* pHeadC  = pw + 8 * 16384;
    u16* pHeadM  = pw + 9 * 16384;
    u16* xc_bf   = (u16*)(ws + OFF_XC);
    u16* xm_bf   = (u16*)(ws + OFF_XM);
    u16* hc_bf   = (u16*)(ws + OFF_HCB);

    const bool shadow = (ws_size >= WS_SHADOW_NEED);

    float* out     = (float*)d_out;
    float* o_hc2   = out;
    float* o_hm2   = o_hc2 + (size_t)nCard * 128;
    float* o_predc = o_hm2 + (size_t)nMerch * 128;
    float* o_predm = o_predc + (size_t)nCard * 2;
    float* o_riskc = o_predm + (size_t)nMerch * 2;
    float* o_riskm = o_riskc + (size_t)nCard;

    hipMemsetAsync(ws, 0, OFF_CNT_C + (size_t)nCard * sizeof(int), stream);

    PrepArgs pa;
    pa.src_cm = src_cm; pa.dst_cm = dst_cm; pa.src_mc = src_mc; pa.dst_mc = dst_mc;
    pa.cnt_m = cnt_m; pa.bucket_m = bucket_m; pa.cnt_c = cnt_c; pa.bucket_c = bucket_c;
    pa.E = E; pa.nMerch = nMerch; pa.nCard = nCard;
    pa.xc = x_card;  pa.xcb = xc_bf; pa.ncBlk = shadow ? (nCard * 64 / 1024) : 0;
    pa.xm = x_merch; pa.xmb = xm_bf; pa.nmBlk = shadow ? (nMerch * 64 / 1024) : 0;
    pa.pd[0]  = { Wl0_cm,   pWl0_cm,  64, 128, 0 };
    pa.pd[1]  = { Wr0_cm,   pWr0_cm,  64, 128, 0 };
    pa.pd[2]  = { Wl0_mc,   pWl0_mc,  64, 128, 0 };
    pa.pd[3]  = { Wr0_mc,   pWr0_mc,  64, 128, 0 };
    pa.pd[4]  = { Wl1_cm,   pWl1_cm, 128, 128, 0 };
    pa.pd[5]  = { Wr1_cm,   pWr1_cm, 128, 128, 0 };
    pa.pd[6]  = { Wl1_mc,   pWl1_mc, 128, 128, 0 };
    pa.pd[7]  = { Wr1_mc,   pWr1_mc, 128, 128, 0 };
    pa.pd[8]  = { cW1_card, pHeadC,  128,  64, 0 };
    pa.pd[9]  = { rW1,      pHeadC,  128,  64, 4 };
    pa.pd[10] = { cW1_mer,  pHeadM,  128,  64, 0 };
    pa.pd[11] = { rW1,      pHeadM,  128,  64, 4 };
    int prepGrid = NBUILD + NPACK + pa.ncBlk + pa.nmBlk;
    prep<<<prepGrid, 256, 0, stream>>>(pa);

    const int nbM = (nMerch + 63) / 64;   // 782
    const int nbC = (nCard + 63) / 64;    // 1563

    if (shadow) {
        // ---- layer 0 pair (no heads) ----
        SageJob a0 = { xc_bf, bucket_m, cnt_m, pWl0_cm, xm_bf, pWr0_cm, bl0_cm,
                       nullptr, h_m, nullptr, nMerch, 1, nbM,
                       nullptr, nullptr, nullptr, nullptr, nullptr, nullptr, nullptr,
                       nullptr, nullptr };
        SageJob a1 = { xm_bf, bucket_c, cnt_c, pWl0_mc, xc_bf, pWr0_mc, bl0_mc,
                       o_hc2, nullptr, hc_bf, nCard, 0, nbC,
                       nullptr, nullptr, nullptr, nullptr, nullptr, nullptr, nullptr,
                       nullptr, nullptr };
        sage_pair64<<<nbM + nbC, 256, 0, stream>>>(a0, a1);

        // ---- layer 1 pair + fused heads ----
        SageJob b0 = { hc_bf, bucket_m, cnt_m, pWl1_cm, h_m, pWr1_cm, bl1_cm,
                       o_hm2, nullptr, nullptr, nMerch, 1, nbM,
                       pHeadM, cb1_mer, rb1, cW2_mer, cb2_mer, rW2, rb2,
                       o_predm, o_riskm };
        SageJob b1 = { h_m, bucket_c, cnt_c, pWl1_mc, hc_bf, pWr1_mc, bl1_mc,
                       o_hc2, nullptr, nullptr, nCard, 0, nbC,
                       pHeadC, cb1_card, rb1, cW2_card, cb2_card, rW2, rb2,
                       o_predc, o_riskc };
        sage_pair128<<<nbM + nbC, 256, 0, stream>>>(b0, b1);
    } else {
        // fallback: fp32 gathers, in-place h_c update (row-disjoint), separate heads
        sage_fused<u32, 64, true, true, false><<<nbM, 256, 0, stream>>>(
            x_card, bucket_m, cnt_m, pWl0_cm, x_merch, pWr0_cm, bl0_cm, h_m, nMerch);
        sage_fused<u16, 64, true, true, true><<<nbC, 256, 0, stream>>>(
            x_merch, bucket_c, cnt_c, pWl0_mc, x_card, pWr0_mc, bl0_mc, o_hc2, nCard);
        sage_fused<u32, 128, true, false, true><<<nbM, 256, 0, stream>>>(
            o_hc2, bucket_m, cnt_m, pWl1_cm, h_m, pWr1_cm, bl1_cm, o_hm2, nMerch);
        sage_fused<u16, 128, false, true, true><<<nbC, 256, 0, stream>>>(
            h_m, bucket_c, cnt_c, pWl1_mc, o_hc2, pWr1_mc, bl1_mc, o_hc2, nCard);
        HeadJob hc = { o_hc2, pHeadC, cb1_card, rb1, cW2_card, cb2_card, rW2, rb2,
                       o_predc, o_riskc, nCard, nbC };
        HeadJob hm = { o_hm2, pHeadM, cb1_mer, rb1, cW2_mer, cb2_mer, rW2, rb2,
                       o_predm, o_riskm, nMerch, nbM };
        head_pair<<<nbC + nbM, 256, 0, stream>>>(hc, hm);
    }
}